// Round 5
// baseline (269.664 us; speedup 1.0000x reference)
//
#include <hip/hip_runtime.h>
#include <hip/hip_cooperative_groups.h>

namespace cg = cooperative_groups;

#define NN 50000
#define NE 400000
#define NG 64
#define NBK 196    // node buckets of 256
#define GRID 256   // cooperative grid: 1 block/CU
#define GSZ (GRID * 256)
#define EPB2 1563  // edges per block stripe (256*1563 >= NE)

typedef unsigned int uint32;
typedef unsigned short uint16;

// ---------------------------------------------------------------------------
// Linear-GCN collapse (validated rounds 1-4):
//   x3 = A^3 X (W1W2W3) + (A^2 1)(b1^T W2 W3) + (A 1)(b2^T W3) + 1 b3^T
// with A = D^-1/2 (Adj+I) D^-1/2;  z = deg^-1/2 .* y, z' = (z+sum_in z)/deg.
// Round 5: fuse the whole 11-dispatch pipeline into k_pre + one cooperative
// mega-kernel with 6 grid syncs; gather3 fused with pooling (no z3 store).
// ---------------------------------------------------------------------------

struct MegaArgs {
  const float* x;
  const int* src;
  const int* dst;
  const int* batch;
  uint32* bhist;
  uint32* rsv;
  uint32* off;
  uint32* ebuf;
  uint16* csr;
  float* dis2;
  float* r;
  float* A;
  float* B;
  float* C2;
  float* pooled;
  const float* W123;
  const float* bW23;
  const float* bW3;
  const float* b3;
  float* out;
};

static __device__ __forceinline__ float wsum(float v) {
#pragma unroll
  for (int o = 32; o > 0; o >>= 1) v += __shfl_xor(v, o, 64);
  return v;
}

// block 0: zero bhist/rsv/pooled. block 1: collapsed weight products.
__global__ void __launch_bounds__(256) k_pre(const float* __restrict__ W1,
                                             const float* __restrict__ b1,
                                             const float* __restrict__ W2,
                                             const float* __restrict__ b2,
                                             const float* __restrict__ W3,
                                             float* __restrict__ W123,
                                             float* __restrict__ bW23,
                                             float* __restrict__ bW3,
                                             uint32* __restrict__ bhist,
                                             uint32* __restrict__ rsv,
                                             float* __restrict__ pooled) {
  int t = threadIdx.x;
  if (blockIdx.x == 0) {
    bhist[t] = 0u;
    rsv[t] = 0u;
    pooled[t] = 0.f;
    pooled[256 + t] = 0.f;
    return;
  }
  __shared__ float w12[144];
  __shared__ float t48[48];
  if (t < 144) {
    int i = t / 48, k = t % 48;
    float s = 0.f;
    for (int j = 0; j < 24; ++j) s += W1[i * 24 + j] * W2[j * 48 + k];
    w12[t] = s;
  }
  if (t < 48) {
    float s = 0.f;
    for (int j = 0; j < 24; ++j) s += b1[j] * W2[j * 48 + t];
    t48[t] = s;
  }
  __syncthreads();
  if (t < 192) {
    float a0 = 0, a1 = 0, a2 = 0, ab = 0, ab3 = 0;
    for (int k = 0; k < 48; ++k) {
      float w3 = W3[k * 192 + t];
      a0 += w12[k] * w3;
      a1 += w12[48 + k] * w3;
      a2 += w12[96 + k] * w3;
      ab += t48[k] * w3;
      ab3 += b2[k] * w3;
    }
    W123[t] = a0;
    W123[192 + t] = a1;
    W123[384 + t] = a2;
    bW23[t] = ab;
    bW3[t] = ab3;
  }
}

static __device__ __forceinline__ void gather_pass(const uint32* __restrict__ off,
                                                   const uint16* __restrict__ csr,
                                                   const float* __restrict__ dis2,
                                                   const float* __restrict__ zin,
                                                   float* __restrict__ zout, int gt) {
  for (int tid = gt; tid < NN * 4; tid += GSZ) {
    int n = tid >> 2, ln = tid & 3;
    uint32 o0 = off[n], o1 = off[n + 1];
    float4 acc = make_float4(0.f, 0.f, 0.f, 0.f);
    for (uint32 i = o0 + ln; i < o1; i += 4) {
      uint32 s = csr[i];
      float4 v = reinterpret_cast<const float4*>(zin)[s];
      acc.x += v.x; acc.y += v.y; acc.z += v.z; acc.w += v.w;
    }
#pragma unroll
    for (int o = 1; o < 4; o <<= 1) {
      acc.x += __shfl_xor(acc.x, o, 64);
      acc.y += __shfl_xor(acc.y, o, 64);
      acc.z += __shfl_xor(acc.z, o, 64);
      acc.w += __shfl_xor(acc.w, o, 64);
    }
    if (ln == 0) {
      float4 zs = reinterpret_cast<const float4*>(zin)[n];
      float w = dis2[n];
      float4 o4;
      o4.x = (acc.x + zs.x) * w;
      o4.y = (acc.y + zs.y) * w;
      o4.z = (acc.z + zs.z) * w;
      o4.w = (acc.w + zs.w) * w;
      reinterpret_cast<float4*>(zout)[n] = o4;
    }
  }
}

__global__ void __launch_bounds__(256) k_mega(MegaArgs a) {
  cg::grid_group gg = cg::this_grid();
  __shared__ uint32 sh[1024];
  __shared__ uint32 lohi[2];
  const int t = threadIdx.x, b = blockIdx.x;
  const int gt = b * 256 + t;
  const int e0 = b * EPB2;
  const int e1 = (e0 + EPB2 < NE) ? (e0 + EPB2) : NE;

  // ---- Phase A: A = [x|1]; LDS hist of dst>>8 -> bhist ----
  for (int n = gt; n < NN; n += GSZ) {
    float4 v;
    v.x = a.x[3 * n + 0];
    v.y = a.x[3 * n + 1];
    v.z = a.x[3 * n + 2];
    v.w = 1.0f;
    reinterpret_cast<float4*>(a.A)[n] = v;
  }
  sh[t] = 0u;
  __syncthreads();
  for (int i = e0 + t; i < e1; i += 256) atomicAdd(&sh[((uint32)a.dst[i]) >> 8], 1u);
  __syncthreads();
  if (t < NBK && sh[t]) atomicAdd(&a.bhist[t], sh[t]);
  gg.sync();

  // ---- Phase B: local bucket-offset scan; bucket-scatter edges -> ebuf ----
  {
    uint32* sc = sh;            // 256
    uint32* boffL = sh + 256;   // 256
    uint32* cntL = sh + 512;    // 256
    uint32* baseL = sh + 768;   // 256
    uint32 v = (t < NBK) ? a.bhist[t] : 0u;
    sc[t] = v;
    __syncthreads();
    for (int o = 1; o < 256; o <<= 1) {
      uint32 u = (t >= o) ? sc[t - o] : 0u;
      __syncthreads();
      sc[t] += u;
      __syncthreads();
    }
    boffL[t] = sc[t] - v;  // exclusive
    cntL[t] = 0u;
    __syncthreads();
    for (int i = e0 + t; i < e1; i += 256) atomicAdd(&cntL[((uint32)a.dst[i]) >> 8], 1u);
    __syncthreads();
    uint32 c = cntL[t];
    baseL[t] = (t < NBK && c) ? (boffL[t] + atomicAdd(&a.rsv[t], c)) : 0u;
    __syncthreads();
    cntL[t] = 0u;
    __syncthreads();
    for (int i = e0 + t; i < e1; i += 256) {
      uint32 s = (uint32)a.src[i], d = (uint32)a.dst[i], bb = d >> 8;
      uint32 slot = baseL[bb] + atomicAdd(&cntL[bb], 1u);
      a.ebuf[slot] = s | ((d & 255u) << 16);
    }
  }
  gg.sync();

  // ---- Phase C: per-bucket CSR build + degrees + fold z0 = y0*deg^-1/2 ----
  if (b == 0 && t == 0) a.off[NN] = NE;
  if (b < NBK) {
    uint32* cnt = sh;          // 256
    uint32* scn = sh + 256;    // 256
    uint32* bsc = sh + 512;    // 256
    uint32 v = (t < NBK) ? a.bhist[t] : 0u;
    bsc[t] = v;
    __syncthreads();
    for (int o = 1; o < 256; o <<= 1) {
      uint32 u = (t >= o) ? bsc[t - o] : 0u;
      __syncthreads();
      bsc[t] += u;
      __syncthreads();
    }
    if (t == b) { lohi[0] = bsc[t] - v; lohi[1] = bsc[t]; }
    cnt[t] = 0u;
    __syncthreads();
    uint32 lo = lohi[0], hi = lohi[1];
    for (uint32 i = lo + t; i < hi; i += 256) atomicAdd(&cnt[a.ebuf[i] >> 16], 1u);
    __syncthreads();
    uint32 c = cnt[t];
    scn[t] = c;
    __syncthreads();
    for (int o = 1; o < 256; o <<= 1) {
      uint32 u = (t >= o) ? scn[t - o] : 0u;
      __syncthreads();
      scn[t] += u;
      __syncthreads();
    }
    uint32 excl = scn[t] - c;
    cnt[t] = excl;  // becomes local cursor
    int n = b * 256 + t;
    if (n < NN) {
      a.off[n] = lo + excl;
      float deg = (float)(c + 1u);
      float ds = rsqrtf(deg);
      a.dis2[n] = 1.0f / deg;
      a.r[n] = sqrtf(deg);
      float4 v4 = reinterpret_cast<const float4*>(a.A)[n];
      v4.x *= ds; v4.y *= ds; v4.z *= ds; v4.w *= ds;
      reinterpret_cast<float4*>(a.A)[n] = v4;
    }
    __syncthreads();
    for (uint32 i = lo + t; i < hi; i += 256) {
      uint32 p = a.ebuf[i];
      uint32 slot = atomicAdd(&cnt[p >> 16], 1u);
      a.csr[lo + slot] = (uint16)p;
    }
  }
  gg.sync();

  // ---- Phases D, E: z0 -> z1 -> z2 ----
  gather_pass(a.off, a.csr, a.dis2, a.A, a.B, gt);
  gg.sync();
  gather_pass(a.off, a.csr, a.dis2, a.B, a.C2, gt);
  gg.sync();

  // ---- Phase F: z2 -> z3 in registers, fused pooling ----
  for (int tid = gt; tid < NN * 4; tid += GSZ) {
    int n = tid >> 2, ln = tid & 3;
    uint32 o0 = a.off[n], o1 = a.off[n + 1];
    float4 acc = make_float4(0.f, 0.f, 0.f, 0.f);
    for (uint32 i = o0 + ln; i < o1; i += 4) {
      uint32 s = a.csr[i];
      float4 v = reinterpret_cast<const float4*>(a.C2)[s];
      acc.x += v.x; acc.y += v.y; acc.z += v.z; acc.w += v.w;
    }
#pragma unroll
    for (int o = 1; o < 4; o <<= 1) {
      acc.x += __shfl_xor(acc.x, o, 64);
      acc.y += __shfl_xor(acc.y, o, 64);
      acc.z += __shfl_xor(acc.z, o, 64);
    }
    int g2 = a.batch[n];
    float vx = 0, vy = 0, vz = 0, v1 = 0, v2 = 0, cc = 0;
    if (ln == 0) {
      float4 zs = reinterpret_cast<const float4*>(a.C2)[n];
      float wr = a.dis2[n] * a.r[n];
      vx = (acc.x + zs.x) * wr;
      vy = (acc.y + zs.y) * wr;
      vz = (acc.z + zs.z) * wr;
      float rr = a.r[n];
      v1 = a.C2[4 * n + 3] * rr;  // A^2 1
      v2 = a.B[4 * n + 3] * rr;   // A 1
      cc = 1.0f;
    }
    int g0 = __shfl(g2, 0, 64);
    bool uni = __all(g2 == g0);
    if (uni) {
      float sx = wsum(vx), sy = wsum(vy), sz = wsum(vz);
      float s1 = wsum(v1), s2 = wsum(v2), sc2 = wsum(cc);
      if ((t & 63) == 0) {
        float* p = a.pooled + 8 * g0;
        atomicAdd(p + 0, sx); atomicAdd(p + 1, sy); atomicAdd(p + 2, sz);
        atomicAdd(p + 3, s1); atomicAdd(p + 4, s2); atomicAdd(p + 5, sc2);
      }
    } else if (ln == 0) {
      float* p = a.pooled + 8 * g2;
      atomicAdd(p + 0, vx); atomicAdd(p + 1, vy); atomicAdd(p + 2, vz);
      atomicAdd(p + 3, v1); atomicAdd(p + 4, v2); atomicAdd(p + 5, cc);
    }
  }
  gg.sync();

  // ---- Phase G: final 64x192 combine ----
  if (b < NG && t < 192) {
    const float* p = a.pooled + 8 * b;
    float cn = __hip_atomic_load(p + 5, __ATOMIC_RELAXED, __HIP_MEMORY_SCOPE_AGENT);
    float ic = 1.0f / fmaxf(cn, 1.0f);
    float sx = __hip_atomic_load(p + 0, __ATOMIC_RELAXED, __HIP_MEMORY_SCOPE_AGENT) * ic;
    float sy = __hip_atomic_load(p + 1, __ATOMIC_RELAXED, __HIP_MEMORY_SCOPE_AGENT) * ic;
    float sz = __hip_atomic_load(p + 2, __ATOMIC_RELAXED, __HIP_MEMORY_SCOPE_AGENT) * ic;
    float v1 = __hip_atomic_load(p + 3, __ATOMIC_RELAXED, __HIP_MEMORY_SCOPE_AGENT) * ic;
    float v2 = __hip_atomic_load(p + 4, __ATOMIC_RELAXED, __HIP_MEMORY_SCOPE_AGENT) * ic;
    a.out[b * 192 + t] = sx * a.W123[t] + sy * a.W123[192 + t] + sz * a.W123[384 + t] +
                         v1 * a.bW23[t] + v2 * a.bW3[t] + a.b3[t];
  }
}

extern "C" void kernel_launch(void* const* d_in, const int* in_sizes, int n_in,
                              void* d_out, int out_size, void* d_ws, size_t ws_size,
                              hipStream_t stream) {
  const float* x = (const float*)d_in[0];   // [NN,3]
  const int* edges = (const int*)d_in[1];   // [2,NE]
  const int* batch = (const int*)d_in[2];   // [NN]
  const float* W1 = (const float*)d_in[3];
  const float* b1 = (const float*)d_in[4];
  const float* W2 = (const float*)d_in[5];
  const float* b2 = (const float*)d_in[6];
  const float* W3 = (const float*)d_in[7];
  const float* b3 = (const float*)d_in[8];
  float* out = (float*)d_out;

  const int* src = edges;
  const int* dst = edges + NE;

  float* ws = (float*)d_ws;
  uint32* bhist = (uint32*)ws;              // [256]
  uint32* rsv = (uint32*)(ws + 256);        // [256]
  uint32* off = (uint32*)(ws + 512);        // [50001] pad 50004
  uint32* ebuf = (uint32*)(ws + 50516);     // [NE]
  uint16* csr = (uint16*)(ws + 450516);     // [NE] u16 (200000 words)
  float* dis2 = ws + 650516;                // [NN]
  float* r = ws + 700516;                   // [NN]
  float* A = ws + 750516;                   // [NN*4]  y0 -> z0
  float* B = ws + 950516;                   // [NN*4]  z1
  float* C2 = ws + 1150516;                 // [NN*4]  z2
  float* pooled = ws + 1350516;             // [512]
  float* W123 = ws + 1351028;               // [576]
  float* bW23 = ws + 1351604;               // [192]
  float* bW3 = ws + 1351796;                // [192]

  k_pre<<<2, 256, 0, stream>>>(W1, b1, W2, b2, W3, W123, bW23, bW3, bhist, rsv, pooled);

  MegaArgs ma;
  ma.x = x; ma.src = src; ma.dst = dst; ma.batch = batch;
  ma.bhist = bhist; ma.rsv = rsv; ma.off = off; ma.ebuf = ebuf; ma.csr = csr;
  ma.dis2 = dis2; ma.r = r; ma.A = A; ma.B = B; ma.C2 = C2; ma.pooled = pooled;
  ma.W123 = W123; ma.bW23 = bW23; ma.bW3 = bW3; ma.b3 = b3; ma.out = out;
  void* kp[] = {&ma};
  hipLaunchCooperativeKernel((void*)k_mega, dim3(GRID), dim3(256), kp, 0, stream);
}

// Round 6
// 68.886 us; speedup vs baseline: 3.9146x; 3.9146x over previous
//
#include <hip/hip_runtime.h>

#define NN 50000
#define NE 400000
#define NG 64
#define NBK 196   // node buckets of 256 (ceil(NN/256))
#define SB 98     // scatter blocks
#define EPB 4096  // edges per scatter block (SB*EPB >= NE)

typedef unsigned int uint32;
typedef unsigned short uint16;

// ---------------------------------------------------------------------------
// Linear-GCN collapse (validated rounds 1-5, absmax ~2e-6):
//   x3 = A^3 X (W1W2W3) + (A^2 1)(b1^T W2 W3) + (A 1)(b2^T W3) + 1 b3^T
// with A = D^-1/2 (Adj+I) D^-1/2;  z = deg^-1/2 .* y, z' = (z+sum_in z)/deg.
// Round 6: round-4 split structure (full occupancy per kernel — the coop
// mega-kernel's 1-wave/SIMD occupancy was an 3.4x regression), with 3 fusions:
//   - k_init absorbs weight-collapse + zeroing (block 196)
//   - k_boff deleted (bscat/csr blocks recompute the 196-scan in LDS)
//   - pooling fused into gather pass 3 (z3 never stored)
// 11 -> 8 dispatches.
// ---------------------------------------------------------------------------

static __device__ __forceinline__ float wsum(float v) {
#pragma unroll
  for (int o = 32; o > 0; o >>= 1) v += __shfl_xor(v, o, 64);
  return v;
}

// blocks 0..195: A = [x|1]; block 0 zeroes bhist/rsv/pooled;
// block 196: collapsed weight products.
__global__ void __launch_bounds__(256) k_init(
    const float* __restrict__ x, const float* __restrict__ W1,
    const float* __restrict__ b1, const float* __restrict__ W2,
    const float* __restrict__ b2, const float* __restrict__ W3,
    float* __restrict__ W123, float* __restrict__ bW23, float* __restrict__ bW3,
    uint32* __restrict__ bhist, uint32* __restrict__ rsv,
    float* __restrict__ pooled, float* __restrict__ A) {
  int t = threadIdx.x, b = blockIdx.x;
  if (b == NBK) {  // weights block
    __shared__ float w12[144];
    __shared__ float t48[48];
    if (t < 144) {
      int i = t / 48, k = t % 48;
      float s = 0.f;
      for (int j = 0; j < 24; ++j) s += W1[i * 24 + j] * W2[j * 48 + k];
      w12[t] = s;
    }
    if (t < 48) {
      float s = 0.f;
      for (int j = 0; j < 24; ++j) s += b1[j] * W2[j * 48 + t];
      t48[t] = s;
    }
    __syncthreads();
    if (t < 192) {
      float a0 = 0, a1 = 0, a2 = 0, ab = 0, ab3 = 0;
      for (int k = 0; k < 48; ++k) {
        float w3 = W3[k * 192 + t];
        a0 += w12[k] * w3;
        a1 += w12[48 + k] * w3;
        a2 += w12[96 + k] * w3;
        ab += t48[k] * w3;
        ab3 += b2[k] * w3;
      }
      W123[t] = a0;
      W123[192 + t] = a1;
      W123[384 + t] = a2;
      bW23[t] = ab;
      bW3[t] = ab3;
    }
    return;
  }
  if (b == 0) {
    bhist[t] = 0u;
    rsv[t] = 0u;
    pooled[t] = 0.f;
    pooled[256 + t] = 0.f;
  }
  int n = b * 256 + t;
  if (n < NN) {
    float4 v;
    v.x = x[3 * n + 0];
    v.y = x[3 * n + 1];
    v.z = x[3 * n + 2];
    v.w = 1.0f;
    reinterpret_cast<float4*>(A)[n] = v;
  }
}

// per-block LDS histogram of dst>>8, merged globally (64 blocks x 196 bins)
__global__ void __launch_bounds__(256) k_hist(const int* __restrict__ dst,
                                              uint32* __restrict__ bhist) {
  __shared__ uint32 h[NBK];
  int t = threadIdx.x;
  if (t < NBK) h[t] = 0u;
  __syncthreads();
  for (int i = blockIdx.x * 256 + t; i < NE; i += gridDim.x * 256)
    atomicAdd(&h[((uint32)dst[i]) >> 8], 1u);
  __syncthreads();
  if (t < NBK && h[t]) atomicAdd(&bhist[t], h[t]);
}

// bucket-partition edges: local LDS scan of bhist for bases, LDS counts,
// one global reservation per (block,bucket), LDS-cursor placement.
// ebuf entry = src | (dst&255)<<16.
__global__ void __launch_bounds__(256) k_bscat(const int* __restrict__ src,
                                               const int* __restrict__ dst,
                                               const uint32* __restrict__ bhist,
                                               uint32* __restrict__ rsv,
                                               uint32* __restrict__ ebuf) {
  __shared__ uint32 boffL[256];
  __shared__ uint32 cnt[256];
  __shared__ uint32 base[256];
  int t = threadIdx.x;
  // local exclusive scan of bhist -> boffL
  uint32 v = (t < NBK) ? bhist[t] : 0u;
  boffL[t] = v;
  __syncthreads();
  for (int o = 1; o < 256; o <<= 1) {
    uint32 u = (t >= o) ? boffL[t - o] : 0u;
    __syncthreads();
    boffL[t] += u;
    __syncthreads();
  }
  uint32 excl = boffL[t] - v;
  __syncthreads();
  boffL[t] = excl;
  cnt[t] = 0u;
  __syncthreads();
  uint32 pk[16];
  uint32 bk[16];
  int e0 = blockIdx.x * EPB + t;
#pragma unroll
  for (int k = 0; k < 16; ++k) {
    int e = e0 + k * 256;
    uint32 b = 0xFFFFFFFFu, p = 0u;
    if (e < NE) {
      uint32 s = (uint32)src[e], d = (uint32)dst[e];
      b = d >> 8;
      p = s | ((d & 255u) << 16);
      atomicAdd(&cnt[b], 1u);
    }
    pk[k] = p;
    bk[k] = b;
  }
  __syncthreads();
  if (t < NBK) {
    uint32 c = cnt[t];
    base[t] = c ? (boffL[t] + atomicAdd(&rsv[t], c)) : 0u;
    cnt[t] = 0u;
  }
  __syncthreads();
#pragma unroll
  for (int k = 0; k < 16; ++k) {
    if (bk[k] != 0xFFFFFFFFu) {
      uint32 slot = base[bk[k]] + atomicAdd(&cnt[bk[k]], 1u);
      ebuf[slot] = pk[k];
    }
  }
}

// one block per bucket: local scan of bhist for lo/hi; LDS degree count +
// scan -> off/csr (u16 src ids); deg -> dis2, r; fold z0 = y0*deg^-1/2.
__global__ void __launch_bounds__(256) k_csr(const uint32* __restrict__ bhist,
                                             const uint32* __restrict__ ebuf,
                                             uint16* __restrict__ csr,
                                             uint32* __restrict__ off,
                                             float* __restrict__ dis2,
                                             float* __restrict__ r,
                                             float* __restrict__ A) {
  __shared__ uint32 cnt[256];
  __shared__ uint32 scn[256];
  __shared__ uint32 lohi[2];
  int b = blockIdx.x, t = threadIdx.x;
  // local scan of bhist to find this bucket's [lo, hi)
  uint32 v = (t < NBK) ? bhist[t] : 0u;
  scn[t] = v;
  __syncthreads();
  for (int o = 1; o < 256; o <<= 1) {
    uint32 u = (t >= o) ? scn[t - o] : 0u;
    __syncthreads();
    scn[t] += u;
    __syncthreads();
  }
  if (t == b) { lohi[0] = scn[t] - v; lohi[1] = scn[t]; }
  cnt[t] = 0u;
  __syncthreads();
  uint32 lo = lohi[0], hi = lohi[1];
  for (uint32 i = lo + t; i < hi; i += 256) atomicAdd(&cnt[ebuf[i] >> 16], 1u);
  __syncthreads();
  uint32 c = cnt[t];
  scn[t] = c;
  __syncthreads();
  for (int o = 1; o < 256; o <<= 1) {
    uint32 u = (t >= o) ? scn[t - o] : 0u;
    __syncthreads();
    scn[t] += u;
    __syncthreads();
  }
  uint32 excl = scn[t] - c;
  cnt[t] = excl;  // becomes local cursor
  int n = b * 256 + t;
  if (n < NN) {
    off[n] = lo + excl;
    float deg = (float)(c + 1u);
    float ds = rsqrtf(deg);
    dis2[n] = 1.0f / deg;
    r[n] = sqrtf(deg);
    float4 v4 = reinterpret_cast<const float4*>(A)[n];
    v4.x *= ds; v4.y *= ds; v4.z *= ds; v4.w *= ds;
    reinterpret_cast<float4*>(A)[n] = v4;
  }
  if (b == 0 && t == 0) off[NN] = NE;
  __syncthreads();
  for (uint32 i = lo + t; i < hi; i += 256) {
    uint32 p = ebuf[i];
    uint32 slot = atomicAdd(&cnt[p >> 16], 1u);
    csr[lo + slot] = (uint16)p;
  }
}

// 4 lanes per node: z'[n] = dis2[n] * (z[n] + sum_{s in csr[off[n]:off[n+1]]} z[s])
__global__ void k_gather(const uint32* __restrict__ off, const uint16* __restrict__ csr,
                         const float* __restrict__ dis2, const float* __restrict__ zin,
                         float* __restrict__ zout) {
  int tid = blockIdx.x * blockDim.x + threadIdx.x;
  int n = tid >> 2, ln = tid & 3;
  if (n >= NN) return;
  uint32 a = off[n], b = off[n + 1];
  float4 acc = make_float4(0.f, 0.f, 0.f, 0.f);
  for (uint32 i = a + ln; i < b; i += 4) {
    uint32 s = csr[i];
    float4 v = reinterpret_cast<const float4*>(zin)[s];
    acc.x += v.x; acc.y += v.y; acc.z += v.z; acc.w += v.w;
  }
#pragma unroll
  for (int o = 1; o < 4; o <<= 1) {
    acc.x += __shfl_xor(acc.x, o, 64);
    acc.y += __shfl_xor(acc.y, o, 64);
    acc.z += __shfl_xor(acc.z, o, 64);
    acc.w += __shfl_xor(acc.w, o, 64);
  }
  if (ln == 0) {
    float4 zs = reinterpret_cast<const float4*>(zin)[n];
    float w = dis2[n];
    float4 o4;
    o4.x = (acc.x + zs.x) * w;
    o4.y = (acc.y + zs.y) * w;
    o4.z = (acc.z + zs.z) * w;
    o4.w = (acc.w + zs.w) * w;
    reinterpret_cast<float4*>(zout)[n] = o4;
  }
}

// third gather pass fused with pooling: z3 stays in registers.
// pooled[g] += (z3.xyz * r, z2.w * r, z1.w * r, 1) per node.
__global__ void k_gather3_pool(const uint32* __restrict__ off,
                               const uint16* __restrict__ csr,
                               const float* __restrict__ dis2,
                               const float* __restrict__ r,
                               const int* __restrict__ batch,
                               const float* __restrict__ B,   // z1
                               const float* __restrict__ C2,  // z2
                               float* __restrict__ pooled) {
  int tid = blockIdx.x * blockDim.x + threadIdx.x;
  int n = tid >> 2, ln = tid & 3;
  if (n >= NN) return;
  uint32 a = off[n], b = off[n + 1];
  float ax = 0.f, ay = 0.f, az = 0.f;
  for (uint32 i = a + ln; i < b; i += 4) {
    uint32 s = csr[i];
    float4 v = reinterpret_cast<const float4*>(C2)[s];
    ax += v.x; ay += v.y; az += v.z;
  }
#pragma unroll
  for (int o = 1; o < 4; o <<= 1) {
    ax += __shfl_xor(ax, o, 64);
    ay += __shfl_xor(ay, o, 64);
    az += __shfl_xor(az, o, 64);
  }
  int g = batch[n];
  float vx = 0, vy = 0, vz = 0, v1 = 0, v2 = 0, cc = 0;
  if (ln == 0) {
    float4 zs = reinterpret_cast<const float4*>(C2)[n];
    float rr = r[n];
    float wr = dis2[n] * rr;
    vx = (ax + zs.x) * wr;
    vy = (ay + zs.y) * wr;
    vz = (az + zs.z) * wr;
    v1 = zs.w * rr;            // z2.w * r = (A^2 1)[n]
    v2 = B[4 * n + 3] * rr;    // z1.w * r = (A 1)[n]
    cc = 1.0f;
  }
  int g0 = __shfl(g, 0, 64);
  bool uni = __all(g == g0);
  if (uni) {
    float sx = wsum(vx), sy = wsum(vy), sz = wsum(vz);
    float s1 = wsum(v1), s2 = wsum(v2), sc = wsum(cc);
    if ((threadIdx.x & 63) == 0) {
      float* p = pooled + 8 * g0;
      atomicAdd(p + 0, sx); atomicAdd(p + 1, sy); atomicAdd(p + 2, sz);
      atomicAdd(p + 3, s1); atomicAdd(p + 4, s2); atomicAdd(p + 5, sc);
    }
  } else if (ln == 0) {
    float* p = pooled + 8 * g;
    atomicAdd(p + 0, vx); atomicAdd(p + 1, vy); atomicAdd(p + 2, vz);
    atomicAdd(p + 3, v1); atomicAdd(p + 4, v2); atomicAdd(p + 5, cc);
  }
}

__global__ void k_final(const float* __restrict__ pooled, const float* __restrict__ W123,
                        const float* __restrict__ bW23, const float* __restrict__ bW3,
                        const float* __restrict__ b3, float* __restrict__ out) {
  int g = blockIdx.x;   // 64
  int l = threadIdx.x;  // 192
  const float* p = pooled + 8 * g;
  float ic = 1.0f / fmaxf(p[5], 1.0f);
  float sx = p[0] * ic, sy = p[1] * ic, sz = p[2] * ic;
  float v1 = p[3] * ic, v2 = p[4] * ic;
  out[g * 192 + l] = sx * W123[l] + sy * W123[192 + l] + sz * W123[384 + l] +
                     v1 * bW23[l] + v2 * bW3[l] + b3[l];
}

extern "C" void kernel_launch(void* const* d_in, const int* in_sizes, int n_in,
                              void* d_out, int out_size, void* d_ws, size_t ws_size,
                              hipStream_t stream) {
  const float* x = (const float*)d_in[0];   // [NN,3]
  const int* edges = (const int*)d_in[1];   // [2,NE]
  const int* batch = (const int*)d_in[2];   // [NN]
  const float* W1 = (const float*)d_in[3];
  const float* b1 = (const float*)d_in[4];
  const float* W2 = (const float*)d_in[5];
  const float* b2 = (const float*)d_in[6];
  const float* W3 = (const float*)d_in[7];
  const float* b3 = (const float*)d_in[8];
  float* out = (float*)d_out;

  const int* src = edges;
  const int* dst = edges + NE;

  float* ws = (float*)d_ws;
  uint32* bhist = (uint32*)ws;              // [256]
  uint32* rsv = (uint32*)(ws + 256);        // [256]
  uint32* off = (uint32*)(ws + 512);        // [50001] pad 50004
  uint32* ebuf = (uint32*)(ws + 50516);     // [NE]
  uint16* csr = (uint16*)(ws + 450516);     // [NE] u16 (200000 words)
  float* dis2 = ws + 650516;                // [NN]
  float* r = ws + 700516;                   // [NN]
  float* A = ws + 750516;                   // [NN*4]  y0 -> z0
  float* B = ws + 950516;                   // [NN*4]  z1
  float* C2 = ws + 1150516;                 // [NN*4]  z2
  float* pooled = ws + 1350516;             // [512]
  float* W123 = ws + 1351028;               // [576]
  float* bW23 = ws + 1351604;               // [192]
  float* bW3 = ws + 1351796;                // [192]

  dim3 b256(256);
  dim3 bg((NN * 4 + 255) / 256);

  k_init<<<NBK + 1, b256, 0, stream>>>(x, W1, b1, W2, b2, W3, W123, bW23, bW3,
                                       bhist, rsv, pooled, A);
  k_hist<<<64, b256, 0, stream>>>(dst, bhist);
  k_bscat<<<SB, b256, 0, stream>>>(src, dst, bhist, rsv, ebuf);
  k_csr<<<NBK, b256, 0, stream>>>(bhist, ebuf, csr, off, dis2, r, A);

  k_gather<<<bg, b256, 0, stream>>>(off, csr, dis2, A, B);   // z0 -> z1
  k_gather<<<bg, b256, 0, stream>>>(off, csr, dis2, B, C2);  // z1 -> z2
  k_gather3_pool<<<bg, b256, 0, stream>>>(off, csr, dis2, r, batch, B, C2, pooled);

  k_final<<<NG, 192, 0, stream>>>(pooled, W123, bW23, bW3, b3, out);
}

// Round 7
// 61.330 us; speedup vs baseline: 4.3969x; 1.1232x over previous
//
#include <hip/hip_runtime.h>

#define NN 50000
#define NE 400000
#define NG 64
#define NBK 196    // node buckets of 256 (ceil(NN/256))
#define CAP 2560   // fixed edge capacity per bucket (mean 2048, sd ~45; >11 sigma)
#define SB 98      // scatter blocks
#define EPB 4096   // edges per scatter block (SB*EPB >= NE)

typedef unsigned int uint32;
typedef unsigned short uint16;

// ---------------------------------------------------------------------------
// Linear-GCN collapse (validated rounds 1-6, absmax ~2e-6):
//   x3 = A^3 X (W1W2W3) + (A^2 1)(b1^T W2 W3) + (A 1)(b2^T W3) + 1 b3^T
// with A = D^-1/2 (Adj+I) D^-1/2;  z = deg^-1/2 .* y, z' = (z+sum_in z)/deg.
// Round 7: fixed-capacity buckets (base = b*CAP) delete k_hist and all
// bucket-offset scans; 8 -> 7 dispatches, all at full per-kernel occupancy
// (round-5 lesson: never trade occupancy for dispatch count).
// ---------------------------------------------------------------------------

static __device__ __forceinline__ float wsum(float v) {
#pragma unroll
  for (int o = 32; o > 0; o >>= 1) v += __shfl_xor(v, o, 64);
  return v;
}

// blocks 0..195: A = [x|1]; block 0 zeroes rsv/pooled; block 196: weights.
__global__ void __launch_bounds__(256) k_init(
    const float* __restrict__ x, const float* __restrict__ W1,
    const float* __restrict__ b1, const float* __restrict__ W2,
    const float* __restrict__ b2, const float* __restrict__ W3,
    float* __restrict__ W123, float* __restrict__ bW23, float* __restrict__ bW3,
    uint32* __restrict__ rsv, float* __restrict__ pooled, float* __restrict__ A) {
  int t = threadIdx.x, b = blockIdx.x;
  if (b == NBK) {  // weights block
    __shared__ float w12[144];
    __shared__ float t48[48];
    if (t < 144) {
      int i = t / 48, k = t % 48;
      float s = 0.f;
      for (int j = 0; j < 24; ++j) s += W1[i * 24 + j] * W2[j * 48 + k];
      w12[t] = s;
    }
    if (t < 48) {
      float s = 0.f;
      for (int j = 0; j < 24; ++j) s += b1[j] * W2[j * 48 + t];
      t48[t] = s;
    }
    __syncthreads();
    if (t < 192) {
      float a0 = 0, a1 = 0, a2 = 0, ab = 0, ab3 = 0;
      for (int k = 0; k < 48; ++k) {
        float w3 = W3[k * 192 + t];
        a0 += w12[k] * w3;
        a1 += w12[48 + k] * w3;
        a2 += w12[96 + k] * w3;
        ab += t48[k] * w3;
        ab3 += b2[k] * w3;
      }
      W123[t] = a0;
      W123[192 + t] = a1;
      W123[384 + t] = a2;
      bW23[t] = ab;
      bW3[t] = ab3;
    }
    return;
  }
  if (b == 0) {
    rsv[t] = 0u;
    pooled[t] = 0.f;
    pooled[256 + t] = 0.f;
  }
  int n = b * 256 + t;
  if (n < NN) {
    float4 v;
    v.x = x[3 * n + 0];
    v.y = x[3 * n + 1];
    v.z = x[3 * n + 2];
    v.w = 1.0f;
    reinterpret_cast<float4*>(A)[n] = v;
  }
}

// bucket-partition edges into fixed-capacity regions: LDS counts, one global
// reservation per (block,bucket), LDS-cursor placement at b*CAP + base.
// ebuf entry = src | (dst&255)<<16.
__global__ void __launch_bounds__(256) k_bscat(const int* __restrict__ src,
                                               const int* __restrict__ dst,
                                               uint32* __restrict__ rsv,
                                               uint32* __restrict__ ebuf) {
  __shared__ uint32 cnt[256];
  __shared__ uint32 base[256];
  int t = threadIdx.x;
  cnt[t] = 0u;
  __syncthreads();
  uint32 pk[16];
  uint32 bk[16];
  int e0 = blockIdx.x * EPB + t;
#pragma unroll
  for (int k = 0; k < 16; ++k) {
    int e = e0 + k * 256;
    uint32 b = 0xFFFFFFFFu, p = 0u;
    if (e < NE) {
      uint32 s = (uint32)src[e], d = (uint32)dst[e];
      b = d >> 8;
      p = s | ((d & 255u) << 16);
      atomicAdd(&cnt[b], 1u);
    }
    pk[k] = p;
    bk[k] = b;
  }
  __syncthreads();
  {
    uint32 c = cnt[t];
    base[t] = c ? (t * CAP + atomicAdd(&rsv[t], c)) : 0u;
    cnt[t] = 0u;
  }
  __syncthreads();
#pragma unroll
  for (int k = 0; k < 16; ++k) {
    if (bk[k] != 0xFFFFFFFFu) {
      uint32 slot = base[bk[k]] + atomicAdd(&cnt[bk[k]], 1u);
      ebuf[slot] = pk[k];
    }
  }
}

// one block per bucket: LDS degree count + scan over ebuf[b*CAP .. +rsv[b]) ->
// offse (start,end) / csr (u16 src ids); drr = (1/deg, sqrt(deg));
// fold z0 = y0 * deg^-1/2 into A.
__global__ void __launch_bounds__(256) k_csr(const uint32* __restrict__ rsv,
                                             const uint32* __restrict__ ebuf,
                                             uint16* __restrict__ csr,
                                             uint2* __restrict__ offse,
                                             float2* __restrict__ drr,
                                             float* __restrict__ A) {
  __shared__ uint32 cnt[256];
  __shared__ uint32 scn[256];
  int b = blockIdx.x, t = threadIdx.x;
  uint32 lo = (uint32)b * CAP;
  uint32 hi = lo + rsv[b];
  cnt[t] = 0u;
  __syncthreads();
  for (uint32 i = lo + t; i < hi; i += 256) atomicAdd(&cnt[ebuf[i] >> 16], 1u);
  __syncthreads();
  uint32 c = cnt[t];
  scn[t] = c;
  __syncthreads();
  for (int o = 1; o < 256; o <<= 1) {
    uint32 u = (t >= o) ? scn[t - o] : 0u;
    __syncthreads();
    scn[t] += u;
    __syncthreads();
  }
  uint32 excl = scn[t] - c;
  cnt[t] = excl;  // becomes local cursor
  int n = b * 256 + t;
  if (n < NN) {
    uint2 oe;
    oe.x = lo + excl;
    oe.y = lo + excl + c;
    offse[n] = oe;
    float deg = (float)(c + 1u);
    float ds = rsqrtf(deg);
    float2 dr;
    dr.x = 1.0f / deg;
    dr.y = sqrtf(deg);
    drr[n] = dr;
    float4 v4 = reinterpret_cast<const float4*>(A)[n];
    v4.x *= ds; v4.y *= ds; v4.z *= ds; v4.w *= ds;
    reinterpret_cast<float4*>(A)[n] = v4;
  }
  __syncthreads();
  for (uint32 i = lo + t; i < hi; i += 256) {
    uint32 p = ebuf[i];
    uint32 slot = atomicAdd(&cnt[p >> 16], 1u);
    csr[lo + slot] = (uint16)p;
  }
}

// 4 lanes per node: z'[n] = dis2[n] * (z[n] + sum_{s in csr[start:end]} z[s])
__global__ void k_gather(const uint2* __restrict__ offse,
                         const uint16* __restrict__ csr,
                         const float2* __restrict__ drr,
                         const float* __restrict__ zin, float* __restrict__ zout) {
  int tid = blockIdx.x * blockDim.x + threadIdx.x;
  int n = tid >> 2, ln = tid & 3;
  if (n >= NN) return;
  uint2 oe = offse[n];
  float4 acc = make_float4(0.f, 0.f, 0.f, 0.f);
  for (uint32 i = oe.x + ln; i < oe.y; i += 4) {
    uint32 s = csr[i];
    float4 v = reinterpret_cast<const float4*>(zin)[s];
    acc.x += v.x; acc.y += v.y; acc.z += v.z; acc.w += v.w;
  }
#pragma unroll
  for (int o = 1; o < 4; o <<= 1) {
    acc.x += __shfl_xor(acc.x, o, 64);
    acc.y += __shfl_xor(acc.y, o, 64);
    acc.z += __shfl_xor(acc.z, o, 64);
    acc.w += __shfl_xor(acc.w, o, 64);
  }
  if (ln == 0) {
    float4 zs = reinterpret_cast<const float4*>(zin)[n];
    float w = drr[n].x;
    float4 o4;
    o4.x = (acc.x + zs.x) * w;
    o4.y = (acc.y + zs.y) * w;
    o4.z = (acc.z + zs.z) * w;
    o4.w = (acc.w + zs.w) * w;
    reinterpret_cast<float4*>(zout)[n] = o4;
  }
}

// third gather pass fused with pooling: z3 stays in registers.
// pooled[g] += (z3.xyz * r, z2.w * r, z1.w * r, 1) per node.
__global__ void k_gather3_pool(const uint2* __restrict__ offse,
                               const uint16* __restrict__ csr,
                               const float2* __restrict__ drr,
                               const int* __restrict__ batch,
                               const float* __restrict__ B,   // z1
                               const float* __restrict__ C2,  // z2
                               float* __restrict__ pooled) {
  int tid = blockIdx.x * blockDim.x + threadIdx.x;
  int n = tid >> 2, ln = tid & 3;
  if (n >= NN) return;
  uint2 oe = offse[n];
  float ax = 0.f, ay = 0.f, az = 0.f;
  for (uint32 i = oe.x + ln; i < oe.y; i += 4) {
    uint32 s = csr[i];
    float4 v = reinterpret_cast<const float4*>(C2)[s];
    ax += v.x; ay += v.y; az += v.z;
  }
#pragma unroll
  for (int o = 1; o < 4; o <<= 1) {
    ax += __shfl_xor(ax, o, 64);
    ay += __shfl_xor(ay, o, 64);
    az += __shfl_xor(az, o, 64);
  }
  int g = batch[n];
  float vx = 0, vy = 0, vz = 0, v1 = 0, v2 = 0, cc = 0;
  if (ln == 0) {
    float4 zs = reinterpret_cast<const float4*>(C2)[n];
    float2 dr = drr[n];
    float rr = dr.y;
    float wr = dr.x * rr;
    vx = (ax + zs.x) * wr;
    vy = (ay + zs.y) * wr;
    vz = (az + zs.z) * wr;
    v1 = zs.w * rr;            // z2.w * r = (A^2 1)[n]
    v2 = B[4 * n + 3] * rr;    // z1.w * r = (A 1)[n]
    cc = 1.0f;
  }
  int g0 = __shfl(g, 0, 64);
  bool uni = __all(g == g0);
  if (uni) {
    float sx = wsum(vx), sy = wsum(vy), sz = wsum(vz);
    float s1 = wsum(v1), s2 = wsum(v2), sc = wsum(cc);
    if ((threadIdx.x & 63) == 0) {
      float* p = pooled + 8 * g0;
      atomicAdd(p + 0, sx); atomicAdd(p + 1, sy); atomicAdd(p + 2, sz);
      atomicAdd(p + 3, s1); atomicAdd(p + 4, s2); atomicAdd(p + 5, sc);
    }
  } else if (ln == 0) {
    float* p = pooled + 8 * g;
    atomicAdd(p + 0, vx); atomicAdd(p + 1, vy); atomicAdd(p + 2, vz);
    atomicAdd(p + 3, v1); atomicAdd(p + 4, v2); atomicAdd(p + 5, cc);
  }
}

__global__ void k_final(const float* __restrict__ pooled, const float* __restrict__ W123,
                        const float* __restrict__ bW23, const float* __restrict__ bW3,
                        const float* __restrict__ b3, float* __restrict__ out) {
  int g = blockIdx.x;   // 64
  int l = threadIdx.x;  // 192
  const float* p = pooled + 8 * g;
  float ic = 1.0f / fmaxf(p[5], 1.0f);
  float sx = p[0] * ic, sy = p[1] * ic, sz = p[2] * ic;
  float v1 = p[3] * ic, v2 = p[4] * ic;
  out[g * 192 + l] = sx * W123[l] + sy * W123[192 + l] + sz * W123[384 + l] +
                     v1 * bW23[l] + v2 * bW3[l] + b3[l];
}

extern "C" void kernel_launch(void* const* d_in, const int* in_sizes, int n_in,
                              void* d_out, int out_size, void* d_ws, size_t ws_size,
                              hipStream_t stream) {
  const float* x = (const float*)d_in[0];   // [NN,3]
  const int* edges = (const int*)d_in[1];   // [2,NE]
  const int* batch = (const int*)d_in[2];   // [NN]
  const float* W1 = (const float*)d_in[3];
  const float* b1 = (const float*)d_in[4];
  const float* W2 = (const float*)d_in[5];
  const float* b2 = (const float*)d_in[6];
  const float* W3 = (const float*)d_in[7];
  const float* b3 = (const float*)d_in[8];
  float* out = (float*)d_out;

  const int* src = edges;
  const int* dst = edges + NE;

  float* ws = (float*)d_ws;
  uint32* rsv = (uint32*)ws;                 // [256] bucket cursors -> counts
  uint2* offse = (uint2*)(ws + 256);         // [NN] {start,end}
  float2* drr = (float2*)(ws + 100256);      // [NN] {1/deg, sqrt(deg)}
  float* A = ws + 200256;                    // [NN*4]  y0 -> z0
  float* B = ws + 400256;                    // [NN*4]  z1
  float* C2 = ws + 600256;                   // [NN*4]  z2
  uint32* ebuf = (uint32*)(ws + 800256);     // [NBK*CAP] = 501760
  uint16* csr = (uint16*)(ws + 1302016);     // [NBK*CAP] u16 (250880 words)
  float* pooled = ws + 1552896;              // [512]
  float* W123 = ws + 1553408;                // [576]
  float* bW23 = ws + 1553984;                // [192]
  float* bW3 = ws + 1554176;                 // [192]

  dim3 b256(256);
  dim3 bg((NN * 4 + 255) / 256);

  k_init<<<NBK + 1, b256, 0, stream>>>(x, W1, b1, W2, b2, W3, W123, bW23, bW3,
                                       rsv, pooled, A);
  k_bscat<<<SB, b256, 0, stream>>>(src, dst, rsv, ebuf);
  k_csr<<<NBK, b256, 0, stream>>>(rsv, ebuf, csr, offse, drr, A);

  k_gather<<<bg, b256, 0, stream>>>(offse, csr, drr, A, B);   // z0 -> z1
  k_gather<<<bg, b256, 0, stream>>>(offse, csr, drr, B, C2);  // z1 -> z2
  k_gather3_pool<<<bg, b256, 0, stream>>>(offse, csr, drr, batch, B, C2, pooled);

  k_final<<<NG, 192, 0, stream>>>(pooled, W123, bW23, bW3, b3, out);
}